// Round 1
// baseline (1460.698 us; speedup 1.0000x reference)
//
#include <hip/hip_runtime.h>
#include <cstdint>

#define D_IN 512
#define HID1 32
#define HID2 16
#define C_OUT 40

// ---------------- CSR build ----------------

__global__ __launch_bounds__(256) void k_hist(const int* __restrict__ row,
                                              int* __restrict__ cnt, int nnz) {
  int i = blockIdx.x * 256 + threadIdx.x;
  if (i < nnz) atomicAdd(&cnt[row[i]], 1);
}

__global__ __launch_bounds__(256) void k_scan1(const int* __restrict__ cnt,
                                               int* __restrict__ bsum, int n) {
  __shared__ int sd[256];
  int t = threadIdx.x;
  int i = blockIdx.x * 256 + t;
  sd[t] = (i < n) ? cnt[i] : 0;
  __syncthreads();
  for (int s = 128; s > 0; s >>= 1) {
    if (t < s) sd[t] += sd[t + s];
    __syncthreads();
  }
  if (t == 0) bsum[blockIdx.x] = sd[0];
}

__global__ void k_scan2(int* __restrict__ bsum, int nb) {
  if (threadIdx.x == 0 && blockIdx.x == 0) {
    int run = 0;
    for (int b = 0; b < nb; ++b) { int v = bsum[b]; bsum[b] = run; run += v; }
  }
}

__global__ __launch_bounds__(256) void k_scan3(const int* __restrict__ cnt,
                                               const int* __restrict__ bsum,
                                               int* __restrict__ rp,
                                               int* __restrict__ pos,
                                               int n, int nnz) {
  __shared__ int sd[256];
  int t = threadIdx.x;
  int i = blockIdx.x * 256 + t;
  int v = (i < n) ? cnt[i] : 0;
  sd[t] = v;
  __syncthreads();
  for (int s = 1; s < 256; s <<= 1) {
    int tv = 0;
    if (t >= s) tv = sd[t - s];
    __syncthreads();
    if (t >= s) sd[t] += tv;
    __syncthreads();
  }
  int excl = sd[t] - v + bsum[blockIdx.x];
  if (i < n) { rp[i] = excl; pos[i] = excl; }
  if (i == n) rp[n] = nnz;
}

__global__ __launch_bounds__(256) void k_scatter(const int* __restrict__ row,
                                                 const int* __restrict__ col,
                                                 const float* __restrict__ w,
                                                 int* __restrict__ pos,
                                                 int2* __restrict__ cpk, int nnz) {
  int i = blockIdx.x * 256 + threadIdx.x;
  if (i < nnz) {
    int p = atomicAdd(&pos[row[i]], 1);
    cpk[p] = make_int2(col[i], __float_as_int(w[i]));
  }
}

// ---------------- GEMM1: x[n,512] @ W0[512,32] -> out[n,32] ----------------

#define FMA_ROW(i, xv)                                                     \
  acc[i][0] += xv.x * wv0.x + xv.y * wv1.x + xv.z * wv2.x + xv.w * wv3.x;  \
  acc[i][1] += xv.x * wv0.y + xv.y * wv1.y + xv.z * wv2.y + xv.w * wv3.y;  \
  acc[i][2] += xv.x * wv0.z + xv.y * wv1.z + xv.z * wv2.z + xv.w * wv3.z;  \
  acc[i][3] += xv.x * wv0.w + xv.y * wv1.w + xv.z * wv2.w + xv.w * wv3.w;

__global__ __launch_bounds__(256) void k_gemm1(const float* __restrict__ x,
                                               const float* __restrict__ W,
                                               float* __restrict__ out, int n) {
  __shared__ float xs[128 * 68];  // 128 rows x 64 k, stride 68 (pad: bank + 16B align)
  __shared__ float ws[64 * 32];
  const int tid = threadIdx.x;
  const int row0 = blockIdx.x * 128;
  const int c0 = (tid & 7) * 4;  // 8 col-groups of 4
  const int rs = tid >> 3;       // 32 row slots
  float acc[4][4] = {};
  for (int k0 = 0; k0 < D_IN; k0 += 64) {
#pragma unroll
    for (int j = 0; j < 8; ++j) {
      int l = tid + 256 * j;
      int r = l >> 4, p = (l & 15) * 4;
      float4 v = make_float4(0.f, 0.f, 0.f, 0.f);
      if (row0 + r < n)
        v = *(const float4*)(x + (size_t)(row0 + r) * D_IN + k0 + p);
      *(float4*)(xs + r * 68 + p) = v;
    }
#pragma unroll
    for (int j = 0; j < 2; ++j) {
      int l = tid + 256 * j;
      int kk = l >> 3, p = (l & 7) * 4;
      *(float4*)(ws + kk * 32 + p) = *(const float4*)(W + (size_t)(k0 + kk) * HID1 + p);
    }
    __syncthreads();
#pragma unroll
    for (int kk = 0; kk < 64; kk += 4) {
      float4 wv0 = *(const float4*)(ws + (kk + 0) * 32 + c0);
      float4 wv1 = *(const float4*)(ws + (kk + 1) * 32 + c0);
      float4 wv2 = *(const float4*)(ws + (kk + 2) * 32 + c0);
      float4 wv3 = *(const float4*)(ws + (kk + 3) * 32 + c0);
      float4 xv0 = *(const float4*)(xs + (rs + 0) * 68 + kk);
      float4 xv1 = *(const float4*)(xs + (rs + 32) * 68 + kk);
      float4 xv2 = *(const float4*)(xs + (rs + 64) * 68 + kk);
      float4 xv3 = *(const float4*)(xs + (rs + 96) * 68 + kk);
      FMA_ROW(0, xv0)
      FMA_ROW(1, xv1)
      FMA_ROW(2, xv2)
      FMA_ROW(3, xv3)
    }
    __syncthreads();
  }
#pragma unroll
  for (int i = 0; i < 4; ++i) {
    int r = row0 + rs + 32 * i;
    if (r < n) {
      float4 v = make_float4(acc[i][0], acc[i][1], acc[i][2], acc[i][3]);
      *(float4*)(out + (size_t)r * HID1 + c0) = v;
    }
  }
}

// ------- small GEMM: relu(Hin + bprev) @ W[IN,OUT], thread-per-row -------

template <int IN, int OUT>
__global__ __launch_bounds__(256) void k_gemm_small(const float* __restrict__ Hin,
                                                    const float* __restrict__ bprev,
                                                    const float* __restrict__ W,
                                                    float* __restrict__ out, int n) {
  int r = blockIdx.x * 256 + threadIdx.x;
  if (r >= n) return;
  float h[IN];
#pragma unroll
  for (int k = 0; k < IN; k += 4) {
    float4 v = *(const float4*)(Hin + (size_t)r * IN + k);
    h[k + 0] = fmaxf(v.x + bprev[k + 0], 0.f);
    h[k + 1] = fmaxf(v.y + bprev[k + 1], 0.f);
    h[k + 2] = fmaxf(v.z + bprev[k + 2], 0.f);
    h[k + 3] = fmaxf(v.w + bprev[k + 3], 0.f);
  }
  float acc[OUT] = {};
#pragma unroll
  for (int k = 0; k < IN; ++k)
#pragma unroll
    for (int c = 0; c < OUT; ++c)
      acc[c] += h[k] * W[k * OUT + c];
#pragma unroll
  for (int c = 0; c < OUT; c += 4) {
    float4 v = make_float4(acc[c], acc[c + 1], acc[c + 2], acc[c + 3]);
    *(float4*)(out + (size_t)r * OUT + c) = v;
  }
}

// ------- pull-mode SpMM: out[r,c] = sum_{i in row r} w_i * HW[col_i, c] -------

template <int COLS, bool EPI>
__global__ __launch_bounds__(256) void k_spmm(const int* __restrict__ rp,
                                              const int2* __restrict__ cpk,
                                              const float* __restrict__ HW,
                                              const float* __restrict__ bias,
                                              float* __restrict__ out, int n) {
  constexpr int LPR = (COLS == 40) ? 64 : COLS;  // lanes per row
  constexpr int RPW = 64 / LPR;                  // rows per wave
  const int lane = threadIdx.x & 63;
  const int wid = (blockIdx.x * blockDim.x + threadIdx.x) >> 6;
  const int sub = lane / LPR;
  const int c = lane % LPR;
  const int r = wid * RPW + sub;
  if (r >= n) return;
  const int s = rp[r], e = rp[r + 1];
  float acc = 0.f;
  for (int i = s; i < e; ++i) {
    int2 p = cpk[i];
    float w = __int_as_float(p.y);
    if (LPR == COLS || c < COLS)
      acc += HW[(size_t)p.x * COLS + c] * w;
  }
  if (LPR == COLS || c < COLS) {
    if (EPI) acc = fmaxf(acc + bias[c], 0.f);
    out[(size_t)r * COLS + c] = acc;
  }
}

// ---------------- launch ----------------

extern "C" void kernel_launch(void* const* d_in, const int* in_sizes, int n_in,
                              void* d_out, int out_size, void* d_ws, size_t ws_size,
                              hipStream_t stream) {
  const float* x  = (const float*)d_in[0];
  const int* erow = (const int*)d_in[1];
  const int* ecol = (const int*)d_in[2];
  const float* ew = (const float*)d_in[3];
  const float* W0 = (const float*)d_in[4];
  const float* b0 = (const float*)d_in[5];
  const float* W1 = (const float*)d_in[6];
  const float* b1 = (const float*)d_in[7];
  const float* W2 = (const float*)d_in[8];
  const float* b2 = (const float*)d_in[9];
  float* out = (float*)d_out;

  const int n = in_sizes[0] / D_IN;    // 100000
  const int nnz = in_sizes[1];         // 3200000

  char* ws = (char*)d_ws;
  float* A  = (float*)(ws + 0);          // n*40 floats max  (16,000,000 B)
  float* B  = (float*)(ws + 16000000);   // n*32 floats      (12,800,000 B)
  int* cnt  = (int*)(ws + 28800000);     // n ints
  int* rp   = (int*)(ws + 29200000);     // n+1 ints
  int* pos  = (int*)(ws + 29600064);     // n ints
  int* bsum = (int*)(ws + 30000064);     // ~400 ints
  int2* cpk = (int2*)(ws + 30003200);    // nnz int2 (25,600,000 B)

  const int nb = (n + 255) / 256;
  const int eb = (nnz + 255) / 256;

  // CSR build (reused by all 3 layers)
  hipMemsetAsync(cnt, 0, (size_t)n * 4, stream);
  k_hist<<<eb, 256, 0, stream>>>(erow, cnt, nnz);
  k_scan1<<<nb, 256, 0, stream>>>(cnt, bsum, n);
  k_scan2<<<1, 64, 0, stream>>>(bsum, nb);
  k_scan3<<<nb, 256, 0, stream>>>(cnt, bsum, rp, pos, n, nnz);
  k_scatter<<<eb, 256, 0, stream>>>(erow, ecol, ew, pos, cpk, nnz);

  // layer 0: HW0 = x@W0 -> A ; agg -> B
  k_gemm1<<<(n + 127) / 128, 256, 0, stream>>>(x, W0, A, n);
  k_spmm<HID1, false><<<(n + 7) / 8, 256, 0, stream>>>(rp, cpk, A, nullptr, B, n);

  // layer 1: HW1 = relu(B+b0)@W1 -> A ; agg -> B
  k_gemm_small<HID1, HID2><<<(n + 255) / 256, 256, 0, stream>>>(B, b0, W1, A, n);
  k_spmm<HID2, false><<<(n + 15) / 16, 256, 0, stream>>>(rp, cpk, A, nullptr, B, n);

  // layer 2: HW2 = relu(B+b1)@W2 -> A ; agg (+b2, relu) -> out
  k_gemm_small<HID2, C_OUT><<<(n + 255) / 256, 256, 0, stream>>>(B, b1, W2, A, n);
  k_spmm<C_OUT, true><<<(n + 3) / 4, 256, 0, stream>>>(rp, cpk, A, b2, out, n);
}

// Round 2
// 1035.983 us; speedup vs baseline: 1.4100x; 1.4100x over previous
//
#include <hip/hip_runtime.h>
#include <cstdint>

#define D_IN 512
#define HID1 32
#define HID2 16
#define C_OUT 40

// ---------------- CSR build ----------------

__global__ __launch_bounds__(256) void k_hist(const int* __restrict__ row,
                                              int* __restrict__ cnt, int nnz) {
  int i = blockIdx.x * 256 + threadIdx.x;
  if (i < nnz) atomicAdd(&cnt[row[i]], 1);
}

__global__ __launch_bounds__(256) void k_scan1(const int* __restrict__ cnt,
                                               int* __restrict__ bsum, int n) {
  __shared__ int sd[256];
  int t = threadIdx.x;
  int i = blockIdx.x * 256 + t;
  sd[t] = (i < n) ? cnt[i] : 0;
  __syncthreads();
  for (int s = 128; s > 0; s >>= 1) {
    if (t < s) sd[t] += sd[t + s];
    __syncthreads();
  }
  if (t == 0) bsum[blockIdx.x] = sd[0];
}

// single-block exclusive scan over nb (<=1024) block sums
__global__ __launch_bounds__(1024) void k_scan2(int* __restrict__ bsum, int nb) {
  __shared__ int sd[1024];
  int t = threadIdx.x;
  int v = (t < nb) ? bsum[t] : 0;
  sd[t] = v;
  __syncthreads();
  for (int s = 1; s < 1024; s <<= 1) {
    int tv = 0;
    if (t >= s) tv = sd[t - s];
    __syncthreads();
    if (t >= s) sd[t] += tv;
    __syncthreads();
  }
  if (t < nb) bsum[t] = sd[t] - v;  // exclusive
}

__global__ __launch_bounds__(256) void k_scan3(const int* __restrict__ cnt,
                                               const int* __restrict__ bsum,
                                               int* __restrict__ rp,
                                               int* __restrict__ pos,
                                               int n, int nnz) {
  __shared__ int sd[256];
  int t = threadIdx.x;
  int i = blockIdx.x * 256 + t;
  int v = (i < n) ? cnt[i] : 0;
  sd[t] = v;
  __syncthreads();
  for (int s = 1; s < 256; s <<= 1) {
    int tv = 0;
    if (t >= s) tv = sd[t - s];
    __syncthreads();
    if (t >= s) sd[t] += tv;
    __syncthreads();
  }
  int excl = sd[t] - v + bsum[blockIdx.x];
  if (i < n) { rp[i] = excl; pos[i] = excl; }
  if (i == n) rp[n] = nnz;
}

__global__ __launch_bounds__(256) void k_scatter(const int* __restrict__ row,
                                                 const int* __restrict__ col,
                                                 const float* __restrict__ w,
                                                 int* __restrict__ pos,
                                                 int2* __restrict__ cpk, int nnz) {
  int i = blockIdx.x * 256 + threadIdx.x;
  if (i < nnz) {
    int p = atomicAdd(&pos[row[i]], 1);
    cpk[p] = make_int2(col[i], __float_as_int(w[i]));
  }
}

// ---------------- GEMM1: x[n,512] @ W0[512,32] -> out[n,32] ----------------

#define FMA_ROW(i, xv)                                                     \
  acc[i][0] += xv.x * wv0.x + xv.y * wv1.x + xv.z * wv2.x + xv.w * wv3.x;  \
  acc[i][1] += xv.x * wv0.y + xv.y * wv1.y + xv.z * wv2.y + xv.w * wv3.y;  \
  acc[i][2] += xv.x * wv0.z + xv.y * wv1.z + xv.z * wv2.z + xv.w * wv3.z;  \
  acc[i][3] += xv.x * wv0.w + xv.y * wv1.w + xv.z * wv2.w + xv.w * wv3.w;

__global__ __launch_bounds__(256) void k_gemm1(const float* __restrict__ x,
                                               const float* __restrict__ W,
                                               float* __restrict__ out, int n) {
  __shared__ float xs[128 * 68];  // 128 rows x 64 k, stride 68
  __shared__ float ws[64 * 32];
  const int tid = threadIdx.x;
  const int row0 = blockIdx.x * 128;
  const int c0 = (tid & 7) * 4;
  const int rs = tid >> 3;
  float acc[4][4] = {};
  for (int k0 = 0; k0 < D_IN; k0 += 64) {
#pragma unroll
    for (int j = 0; j < 8; ++j) {
      int l = tid + 256 * j;
      int r = l >> 4, p = (l & 15) * 4;
      float4 v = make_float4(0.f, 0.f, 0.f, 0.f);
      if (row0 + r < n)
        v = *(const float4*)(x + (size_t)(row0 + r) * D_IN + k0 + p);
      *(float4*)(xs + r * 68 + p) = v;
    }
#pragma unroll
    for (int j = 0; j < 2; ++j) {
      int l = tid + 256 * j;
      int kk = l >> 3, p = (l & 7) * 4;
      *(float4*)(ws + kk * 32 + p) = *(const float4*)(W + (size_t)(k0 + kk) * HID1 + p);
    }
    __syncthreads();
#pragma unroll
    for (int kk = 0; kk < 64; kk += 4) {
      float4 wv0 = *(const float4*)(ws + (kk + 0) * 32 + c0);
      float4 wv1 = *(const float4*)(ws + (kk + 1) * 32 + c0);
      float4 wv2 = *(const float4*)(ws + (kk + 2) * 32 + c0);
      float4 wv3 = *(const float4*)(ws + (kk + 3) * 32 + c0);
      float4 xv0 = *(const float4*)(xs + (rs + 0) * 68 + kk);
      float4 xv1 = *(const float4*)(xs + (rs + 32) * 68 + kk);
      float4 xv2 = *(const float4*)(xs + (rs + 64) * 68 + kk);
      float4 xv3 = *(const float4*)(xs + (rs + 96) * 68 + kk);
      FMA_ROW(0, xv0)
      FMA_ROW(1, xv1)
      FMA_ROW(2, xv2)
      FMA_ROW(3, xv3)
    }
    __syncthreads();
  }
#pragma unroll
  for (int i = 0; i < 4; ++i) {
    int r = row0 + rs + 32 * i;
    if (r < n) {
      float4 v = make_float4(acc[i][0], acc[i][1], acc[i][2], acc[i][3]);
      *(float4*)(out + (size_t)r * HID1 + c0) = v;
    }
  }
}

// ------- small GEMM: (optional pre: relu(Hin+bpre)) @ W, (optional post: relu(+bpost)) -------

template <int IN, int OUT, bool PRE, bool POST>
__global__ __launch_bounds__(256) void k_gemm_small(const float* __restrict__ Hin,
                                                    const float* __restrict__ bpre,
                                                    const float* __restrict__ W,
                                                    const float* __restrict__ bpost,
                                                    float* __restrict__ out, int n) {
  int r = blockIdx.x * 256 + threadIdx.x;
  if (r >= n) return;
  float h[IN];
#pragma unroll
  for (int k = 0; k < IN; k += 4) {
    float4 v = *(const float4*)(Hin + (size_t)r * IN + k);
    if (PRE) {
      h[k + 0] = fmaxf(v.x + bpre[k + 0], 0.f);
      h[k + 1] = fmaxf(v.y + bpre[k + 1], 0.f);
      h[k + 2] = fmaxf(v.z + bpre[k + 2], 0.f);
      h[k + 3] = fmaxf(v.w + bpre[k + 3], 0.f);
    } else {
      h[k + 0] = v.x; h[k + 1] = v.y; h[k + 2] = v.z; h[k + 3] = v.w;
    }
  }
  float acc[OUT] = {};
#pragma unroll
  for (int k = 0; k < IN; ++k)
#pragma unroll
    for (int c = 0; c < OUT; ++c)
      acc[c] += h[k] * W[k * OUT + c];
#pragma unroll
  for (int c = 0; c < OUT; c += 4) {
    float4 v;
    if (POST) {
      v = make_float4(fmaxf(acc[c] + bpost[c], 0.f),
                      fmaxf(acc[c + 1] + bpost[c + 1], 0.f),
                      fmaxf(acc[c + 2] + bpost[c + 2], 0.f),
                      fmaxf(acc[c + 3] + bpost[c + 3], 0.f));
    } else {
      v = make_float4(acc[c], acc[c + 1], acc[c + 2], acc[c + 3]);
    }
    *(float4*)(out + (size_t)r * OUT + c) = v;
  }
}

// ------- pull-mode SpMM, unroll-4 for memory-level parallelism -------
// out[r,c] = sum_{i in row r} w_i * HW[col_i, c]; EPI: out = relu(out + bias)

template <int COLS, bool EPI>
__global__ __launch_bounds__(256) void k_spmm(const int* __restrict__ rp,
                                              const int2* __restrict__ cpk,
                                              const float* __restrict__ HW,
                                              const float* __restrict__ bias,
                                              float* __restrict__ out, int n) {
  constexpr int RPW = 64 / COLS;  // rows per wave (COLS in {16,32})
  const int lane = threadIdx.x & 63;
  const int wid = (blockIdx.x * blockDim.x + threadIdx.x) >> 6;
  const int sub = lane / COLS;
  const int c = lane % COLS;
  const int r = wid * RPW + sub;
  if (r >= n) return;
  const int s = rp[r], e = rp[r + 1];
  float acc = 0.f;
  int i = s;
  for (; i + 4 <= e; i += 4) {
    int2 p0 = cpk[i + 0];
    int2 p1 = cpk[i + 1];
    int2 p2 = cpk[i + 2];
    int2 p3 = cpk[i + 3];
    float v0 = HW[(size_t)p0.x * COLS + c];
    float v1 = HW[(size_t)p1.x * COLS + c];
    float v2 = HW[(size_t)p2.x * COLS + c];
    float v3 = HW[(size_t)p3.x * COLS + c];
    acc = fmaf(v0, __int_as_float(p0.y), acc);
    acc = fmaf(v1, __int_as_float(p1.y), acc);
    acc = fmaf(v2, __int_as_float(p2.y), acc);
    acc = fmaf(v3, __int_as_float(p3.y), acc);
  }
  for (; i < e; ++i) {
    int2 p = cpk[i];
    acc = fmaf(HW[(size_t)p.x * COLS + c], __int_as_float(p.y), acc);
  }
  if (EPI) acc = fmaxf(acc + bias[c], 0.f);
  out[(size_t)r * COLS + c] = acc;
}

// ---------------- launch ----------------
//
// Algebra: A@(H@W) == (A@H)@W (segment_sum is linear). Layer 2 aggregates the
// 16-wide H2 (64 B/edge gather) instead of the 40-wide H2@W2 (160 B/edge).

extern "C" void kernel_launch(void* const* d_in, const int* in_sizes, int n_in,
                              void* d_out, int out_size, void* d_ws, size_t ws_size,
                              hipStream_t stream) {
  const float* x  = (const float*)d_in[0];
  const int* erow = (const int*)d_in[1];
  const int* ecol = (const int*)d_in[2];
  const float* ew = (const float*)d_in[3];
  const float* W0 = (const float*)d_in[4];
  const float* b0 = (const float*)d_in[5];
  const float* W1 = (const float*)d_in[6];
  const float* b1 = (const float*)d_in[7];
  const float* W2 = (const float*)d_in[8];
  const float* b2 = (const float*)d_in[9];
  float* out = (float*)d_out;

  const int n = in_sizes[0] / D_IN;    // 100000
  const int nnz = in_sizes[1];         // 3200000

  char* ws = (char*)d_ws;
  float* A  = (float*)(ws + 0);          // n*32 floats max
  float* B  = (float*)(ws + 16000000);   // n*32 floats
  int* cnt  = (int*)(ws + 28800000);
  int* rp   = (int*)(ws + 29200000);
  int* pos  = (int*)(ws + 29600064);
  int* bsum = (int*)(ws + 30000064);
  int2* cpk = (int2*)(ws + 30003200);    // nnz int2

  const int nb = (n + 255) / 256;
  const int eb = (nnz + 255) / 256;

  // CSR build (reused by all 3 layers)
  hipMemsetAsync(cnt, 0, (size_t)n * 4, stream);
  k_hist<<<eb, 256, 0, stream>>>(erow, cnt, nnz);
  k_scan1<<<nb, 256, 0, stream>>>(cnt, bsum, n);
  k_scan2<<<1, 1024, 0, stream>>>(bsum, nb);
  k_scan3<<<nb, 256, 0, stream>>>(cnt, bsum, rp, pos, n, nnz);
  k_scatter<<<eb, 256, 0, stream>>>(erow, ecol, ew, pos, cpk, nnz);

  // layer 0: P0 = x@W0 -> A ; S0 = A_sp@P0 -> B
  k_gemm1<<<(n + 127) / 128, 256, 0, stream>>>(x, W0, A, n);
  k_spmm<HID1, false><<<(n + 7) / 8, 256, 0, stream>>>(rp, cpk, A, nullptr, B, n);

  // layer 1: P1 = relu(S0+b0)@W1 -> A ; H2 = relu(A_sp@P1 + b1) -> B
  k_gemm_small<HID1, HID2, true, false>
      <<<(n + 255) / 256, 256, 0, stream>>>(B, b0, W1, nullptr, A, n);
  k_spmm<HID2, true><<<(n + 15) / 16, 256, 0, stream>>>(rp, cpk, A, b1, B, n);

  // layer 2 (reassociated): S2 = A_sp@H2 -> A ; out = relu(S2@W2 + b2)
  k_spmm<HID2, false><<<(n + 15) / 16, 256, 0, stream>>>(rp, cpk, B, nullptr, A, n);
  k_gemm_small<HID2, C_OUT, false, true>
      <<<(n + 255) / 256, 256, 0, stream>>>(A, nullptr, W2, b2, out, n);
}

// Round 3
// 911.258 us; speedup vs baseline: 1.6029x; 1.1369x over previous
//
#include <hip/hip_runtime.h>
#include <cstdint>

#define D_IN 512
#define HID1 32
#define HID2 16
#define C_OUT 40

#define GLOAD_LDS16(gp, lp)                                                     \
  __builtin_amdgcn_global_load_lds(                                             \
      (__attribute__((address_space(1))) const void*)(gp),                      \
      (__attribute__((address_space(3))) void*)(lp), 16, 0, 0)

// ---------------- CSR build ----------------

__global__ __launch_bounds__(256) void k_hist(const int* __restrict__ row,
                                              int* __restrict__ cnt, int nnz) {
  int i = blockIdx.x * 256 + threadIdx.x;
  if (i < nnz) atomicAdd(&cnt[row[i]], 1);
}

__global__ __launch_bounds__(256) void k_scan1(const int* __restrict__ cnt,
                                               int* __restrict__ bsum, int n) {
  __shared__ int sd[256];
  int t = threadIdx.x;
  int i = blockIdx.x * 256 + t;
  sd[t] = (i < n) ? cnt[i] : 0;
  __syncthreads();
  for (int s = 128; s > 0; s >>= 1) {
    if (t < s) sd[t] += sd[t + s];
    __syncthreads();
  }
  if (t == 0) bsum[blockIdx.x] = sd[0];
}

// single-block exclusive scan over nb (<=1024) block sums
__global__ __launch_bounds__(1024) void k_scan2(int* __restrict__ bsum, int nb) {
  __shared__ int sd[1024];
  int t = threadIdx.x;
  int v = (t < nb) ? bsum[t] : 0;
  sd[t] = v;
  __syncthreads();
  for (int s = 1; s < 1024; s <<= 1) {
    int tv = 0;
    if (t >= s) tv = sd[t - s];
    __syncthreads();
    if (t >= s) sd[t] += tv;
    __syncthreads();
  }
  if (t < nb) bsum[t] = sd[t] - v;  // exclusive
}

__global__ __launch_bounds__(256) void k_scan3(const int* __restrict__ cnt,
                                               const int* __restrict__ bsum,
                                               int* __restrict__ rp,
                                               int* __restrict__ pos,
                                               int n, int nnz) {
  __shared__ int sd[256];
  int t = threadIdx.x;
  int i = blockIdx.x * 256 + t;
  int v = (i < n) ? cnt[i] : 0;
  sd[t] = v;
  __syncthreads();
  for (int s = 1; s < 256; s <<= 1) {
    int tv = 0;
    if (t >= s) tv = sd[t - s];
    __syncthreads();
    if (t >= s) sd[t] += tv;
    __syncthreads();
  }
  int excl = sd[t] - v + bsum[blockIdx.x];
  if (i < n) { rp[i] = excl; pos[i] = excl; }
  if (i == n) rp[n] = nnz;
}

__global__ __launch_bounds__(256) void k_scatter(const int* __restrict__ row,
                                                 const int* __restrict__ col,
                                                 const float* __restrict__ w,
                                                 int* __restrict__ pos,
                                                 int2* __restrict__ cpk, int nnz) {
  int i = blockIdx.x * 256 + threadIdx.x;
  if (i < nnz) {
    int p = atomicAdd(&pos[row[i]], 1);
    cpk[p] = make_int2(col[i], __float_as_int(w[i]));
  }
}

// ---------------- GEMM1: x[n,512] @ W0[512,32] -> out[n,32] ----------------
// Double-buffered global_load_lds staging (BK=32). LDS dest is linear
// (wave-uniform base + lane*16); the x-tile is XOR-swizzled on the GLOBAL
// source address and un-swizzled on the LDS read so the strided row reads
// (stride 128B) hit distinct banks. W-chunk reads vary within a 128B row ->
// naturally conflict-free, stays linear.

#define FMA_ROW(i, xv)                                                     \
  acc[i][0] += xv.x * wv0.x + xv.y * wv1.x + xv.z * wv2.x + xv.w * wv3.x;  \
  acc[i][1] += xv.x * wv0.y + xv.y * wv1.y + xv.z * wv2.y + xv.w * wv3.y;  \
  acc[i][2] += xv.x * wv0.z + xv.y * wv1.z + xv.z * wv2.z + xv.w * wv3.z;  \
  acc[i][3] += xv.x * wv0.w + xv.y * wv1.w + xv.z * wv2.w + xv.w * wv3.w;

__global__ __launch_bounds__(256) void k_gemm1(const float* __restrict__ x,
                                               const float* __restrict__ W,
                                               float* __restrict__ out, int n) {
  __shared__ float xs[2][128 * 32];  // 16KB per buffer, swizzled storage
  __shared__ float ws[2][32 * 32];   // 4KB per buffer, linear
  const int tid = threadIdx.x;
  const int row0 = blockIdx.x * 128;
  const int c0 = (tid & 7) * 4;   // 8 col-groups of 4
  const int rs = tid >> 3;        // 32 row slots
  const int xsw = (rs & 7) << 4;  // read-side XOR (same for rs, rs+32, ...)
  const int wvb = (tid & 192) * 4;  // wave-uniform float offset into tile
  float acc[4][4] = {};

  // stage chunk k0 into buffer b
#define STAGE(b, k0)                                                         \
  {                                                                          \
    _Pragma("unroll") for (int j = 0; j < 4; ++j) {                          \
      const int L = j * 4096 + tid * 16; /* byte offset in x tile */         \
      const int row = L >> 7;                                                \
      const int src = (L & 127) ^ ((row & 7) << 4);                          \
      int gr = row0 + row;                                                   \
      gr = gr < n ? gr : n - 1;                                              \
      const float* gp = x + (size_t)gr * D_IN + (k0) + (src >> 2);           \
      GLOAD_LDS16(gp, xs[b] + j * 1024 + wvb);                               \
    }                                                                        \
    GLOAD_LDS16(W + (size_t)(k0)*HID1 + tid * 4, ws[b] + wvb);               \
  }

  STAGE(0, 0)
  int cur = 0;
  for (int t = 0; t < D_IN / 32; ++t) {
    __syncthreads();  // drains vmcnt -> buf[cur] ready; prior reads done
    if (t + 1 < D_IN / 32) STAGE(cur ^ 1, (t + 1) * 32)
    const float* wb = ws[cur];
    const char* xb = (const char*)xs[cur];
#pragma unroll
    for (int kk = 0; kk < 32; kk += 4) {
      float4 wv0 = *(const float4*)(wb + (kk + 0) * 32 + c0);
      float4 wv1 = *(const float4*)(wb + (kk + 1) * 32 + c0);
      float4 wv2 = *(const float4*)(wb + (kk + 2) * 32 + c0);
      float4 wv3 = *(const float4*)(wb + (kk + 3) * 32 + c0);
      float4 xv0 = *(const float4*)(xb + (rs + 0) * 128 + ((kk * 4) ^ xsw));
      float4 xv1 = *(const float4*)(xb + (rs + 32) * 128 + ((kk * 4) ^ xsw));
      float4 xv2 = *(const float4*)(xb + (rs + 64) * 128 + ((kk * 4) ^ xsw));
      float4 xv3 = *(const float4*)(xb + (rs + 96) * 128 + ((kk * 4) ^ xsw));
      FMA_ROW(0, xv0)
      FMA_ROW(1, xv1)
      FMA_ROW(2, xv2)
      FMA_ROW(3, xv3)
    }
    cur ^= 1;
  }
#undef STAGE
#pragma unroll
  for (int i = 0; i < 4; ++i) {
    int r = row0 + rs + 32 * i;
    if (r < n) {
      float4 v = make_float4(acc[i][0], acc[i][1], acc[i][2], acc[i][3]);
      *(float4*)(out + (size_t)r * HID1 + c0) = v;
    }
  }
}

// ------- small GEMM: (optional pre: relu(Hin+bpre)) @ W, (optional post: relu(+bpost)) -------

template <int IN, int OUT, bool PRE, bool POST>
__global__ __launch_bounds__(256) void k_gemm_small(const float* __restrict__ Hin,
                                                    const float* __restrict__ bpre,
                                                    const float* __restrict__ W,
                                                    const float* __restrict__ bpost,
                                                    float* __restrict__ out, int n) {
  int r = blockIdx.x * 256 + threadIdx.x;
  if (r >= n) return;
  float h[IN];
#pragma unroll
  for (int k = 0; k < IN; k += 4) {
    float4 v = *(const float4*)(Hin + (size_t)r * IN + k);
    if (PRE) {
      h[k + 0] = fmaxf(v.x + bpre[k + 0], 0.f);
      h[k + 1] = fmaxf(v.y + bpre[k + 1], 0.f);
      h[k + 2] = fmaxf(v.z + bpre[k + 2], 0.f);
      h[k + 3] = fmaxf(v.w + bpre[k + 3], 0.f);
    } else {
      h[k + 0] = v.x; h[k + 1] = v.y; h[k + 2] = v.z; h[k + 3] = v.w;
    }
  }
  float acc[OUT] = {};
#pragma unroll
  for (int k = 0; k < IN; ++k)
#pragma unroll
    for (int c = 0; c < OUT; ++c)
      acc[c] += h[k] * W[k * OUT + c];
#pragma unroll
  for (int c = 0; c < OUT; c += 4) {
    float4 v;
    if (POST) {
      v = make_float4(fmaxf(acc[c] + bpost[c], 0.f),
                      fmaxf(acc[c + 1] + bpost[c + 1], 0.f),
                      fmaxf(acc[c + 2] + bpost[c + 2], 0.f),
                      fmaxf(acc[c + 3] + bpost[c + 3], 0.f));
    } else {
      v = make_float4(acc[c], acc[c + 1], acc[c + 2], acc[c + 3]);
    }
    *(float4*)(out + (size_t)r * OUT + c) = v;
  }
}

// ------- pull-mode SpMM, unroll-8 for memory-level parallelism -------
// out[r,c] = sum_{i in row r} w_i * HW[col_i, c]; EPI: out = relu(out + bias)

template <int COLS, bool EPI>
__global__ __launch_bounds__(256) void k_spmm(const int* __restrict__ rp,
                                              const int2* __restrict__ cpk,
                                              const float* __restrict__ HW,
                                              const float* __restrict__ bias,
                                              float* __restrict__ out, int n) {
  constexpr int RPW = 64 / COLS;  // rows per wave (COLS in {16,32})
  const int lane = threadIdx.x & 63;
  const int wid = (blockIdx.x * blockDim.x + threadIdx.x) >> 6;
  const int sub = lane / COLS;
  const int c = lane % COLS;
  const int r = wid * RPW + sub;
  if (r >= n) return;
  const int s = rp[r], e = rp[r + 1];
  float acc = 0.f;
  int i = s;
  for (; i + 8 <= e; i += 8) {
    int2 p[8];
    float v[8];
#pragma unroll
    for (int u = 0; u < 8; ++u) p[u] = cpk[i + u];
#pragma unroll
    for (int u = 0; u < 8; ++u) v[u] = HW[(size_t)p[u].x * COLS + c];
#pragma unroll
    for (int u = 0; u < 8; ++u) acc = fmaf(v[u], __int_as_float(p[u].y), acc);
  }
  for (; i + 4 <= e; i += 4) {
    int2 p0 = cpk[i + 0], p1 = cpk[i + 1], p2 = cpk[i + 2], p3 = cpk[i + 3];
    float v0 = HW[(size_t)p0.x * COLS + c];
    float v1 = HW[(size_t)p1.x * COLS + c];
    float v2 = HW[(size_t)p2.x * COLS + c];
    float v3 = HW[(size_t)p3.x * COLS + c];
    acc = fmaf(v0, __int_as_float(p0.y), acc);
    acc = fmaf(v1, __int_as_float(p1.y), acc);
    acc = fmaf(v2, __int_as_float(p2.y), acc);
    acc = fmaf(v3, __int_as_float(p3.y), acc);
  }
  for (; i < e; ++i) {
    int2 p = cpk[i];
    acc = fmaf(HW[(size_t)p.x * COLS + c], __int_as_float(p.y), acc);
  }
  if (EPI) acc = fmaxf(acc + bias[c], 0.f);
  out[(size_t)r * COLS + c] = acc;
}

// ---------------- launch ----------------
//
// Algebra: A@(H@W) == (A@H)@W (segment_sum is linear). Layer 2 aggregates the
// 16-wide H2 (64 B/edge gather) instead of the 40-wide H2@W2 (160 B/edge).

extern "C" void kernel_launch(void* const* d_in, const int* in_sizes, int n_in,
                              void* d_out, int out_size, void* d_ws, size_t ws_size,
                              hipStream_t stream) {
  const float* x  = (const float*)d_in[0];
  const int* erow = (const int*)d_in[1];
  const int* ecol = (const int*)d_in[2];
  const float* ew = (const float*)d_in[3];
  const float* W0 = (const float*)d_in[4];
  const float* b0 = (const float*)d_in[5];
  const float* W1 = (const float*)d_in[6];
  const float* b1 = (const float*)d_in[7];
  const float* W2 = (const float*)d_in[8];
  const float* b2 = (const float*)d_in[9];
  float* out = (float*)d_out;

  const int n = in_sizes[0] / D_IN;    // 100000
  const int nnz = in_sizes[1];         // 3200000

  char* ws = (char*)d_ws;
  float* A  = (float*)(ws + 0);          // n*32 floats max
  float* B  = (float*)(ws + 16000000);   // n*32 floats
  int* cnt  = (int*)(ws + 28800000);
  int* rp   = (int*)(ws + 29200000);
  int* pos  = (int*)(ws + 29600064);
  int* bsum = (int*)(ws + 30000064);
  int2* cpk = (int2*)(ws + 30003200);    // nnz int2

  const int nb = (n + 255) / 256;
  const int eb = (nnz + 255) / 256;

  // CSR build (reused by all 3 layers)
  hipMemsetAsync(cnt, 0, (size_t)n * 4, stream);
  k_hist<<<eb, 256, 0, stream>>>(erow, cnt, nnz);
  k_scan1<<<nb, 256, 0, stream>>>(cnt, bsum, n);
  k_scan2<<<1, 1024, 0, stream>>>(bsum, nb);
  k_scan3<<<nb, 256, 0, stream>>>(cnt, bsum, rp, pos, n, nnz);
  k_scatter<<<eb, 256, 0, stream>>>(erow, ecol, ew, pos, cpk, nnz);

  // layer 0: P0 = x@W0 -> A ; S0 = A_sp@P0 -> B
  k_gemm1<<<(n + 127) / 128, 256, 0, stream>>>(x, W0, A, n);
  k_spmm<HID1, false><<<(n + 7) / 8, 256, 0, stream>>>(rp, cpk, A, nullptr, B, n);

  // layer 1: P1 = relu(S0+b0)@W1 -> A ; H2 = relu(A_sp@P1 + b1) -> B
  k_gemm_small<HID1, HID2, true, false>
      <<<(n + 255) / 256, 256, 0, stream>>>(B, b0, W1, nullptr, A, n);
  k_spmm<HID2, true><<<(n + 15) / 16, 256, 0, stream>>>(rp, cpk, A, b1, B, n);

  // layer 2 (reassociated): S2 = A_sp@H2 -> A ; out = relu(S2@W2 + b2)
  k_spmm<HID2, false><<<(n + 15) / 16, 256, 0, stream>>>(rp, cpk, B, nullptr, A, n);
  k_gemm_small<HID2, C_OUT, false, true>
      <<<(n + 255) / 256, 256, 0, stream>>>(A, nullptr, W2, b2, out, n);
}